// Round 5
// baseline (20018.864 us; speedup 1.0000x reference)
//
#include <hip/hip_runtime.h>

// ---------------- problem constants ----------------
constexpr int SEQ = 2048;
constexpr int HD  = 512;     // H = D = DW
constexpr int TH3 = 1536;    // 3H
constexpr int ZT  = 3072;    // combined [W_hh | Ww_hh] output cols
constexpr int KWW = 3;

constexpr int NPART  = 32;         // participating blocks (one XCD: 32 CUs)
constexpr int NT     = 1024;       // threads/block (16 waves)
constexpr int CHB    = 16;         // channels per block (1 per wave)
constexpr int SPB    = SEQ / NPART;// 64 steps/block metadata precompute
constexpr int MAXW   = 16;
constexpr int NLAUNCH= 256;        // launched blocks (1 per CU)
constexpr int SPIN_ESC = 1 << 16;  // poll spin limit before agent-scope escape

constexpr unsigned int SENT  = 0xFFFFFFFFu;  // NaN pattern, unreachable by finite gate math
constexpr unsigned int MAGIC = 0x5A5A0000u;

// ws layout (bytes)
// -- zero-memset region --
constexpr size_t WS_FLAGS  = 0;        // 64 ints (init barrier)
constexpr size_t WS_CNT    = 1024;     // dtype-detect counter
constexpr size_t WS_XCNT   = 1280;     // 8 ints per-XCD arrival counters
constexpr size_t WS_ELECT  = 1312;     // elected xcd+1 (0 = none)
constexpr size_t WS_COHF   = 1316;     // coherence-test failure flag
constexpr size_t WS_COHT   = 1344;     // 64 uints coherence test slots (2 gens)
constexpr size_t WS_ZEROSZ = 2048;
// -- 0xFF-memset region (sentinel-polled buffers) --
constexpr size_t WS_CBUF   = 2048;                               // SEQ*KWW*HD f32
constexpr size_t WS_HFULL  = WS_CBUF + (size_t)SEQ*KWW*HD*4;     // SEQ*HD f32
constexpr size_t WS_FFEND  = WS_HFULL + (size_t)SEQ*HD*4;
// -- plain region --
constexpr size_t WS_MHDR   = ((WS_FFEND + 255)/256)*256;         // SEQ i32
constexpr size_t WS_MROWS  = WS_MHDR + (size_t)SEQ*4;            // SEQ*MAXW i32
constexpr size_t WS_WIB    = WS_MROWS + (size_t)SEQ*MAXW*4;      // SEQ*1536 f32
constexpr size_t WS_AWIB   = WS_WIB  + (size_t)SEQ*TH3*4;        // SEQ*512 f32
constexpr size_t WS_WWIB   = WS_AWIB + (size_t)SEQ*HD*4;         // SEQ*KWW*1536 f32
constexpr size_t WS_WT     = WS_WWIB + (size_t)SEQ*KWW*TH3*4;    // 3072*512 f32 W^T
constexpr size_t WS_END    = WS_WT + (size_t)ZT*HD*4;

__device__ inline float bf2f(unsigned int u) {
    return __builtin_bit_cast(float, u << 16);
}
__device__ inline unsigned short f2bf(float f) {
    unsigned int u = __builtin_bit_cast(unsigned int, f);
    u += 0x7fffu + ((u >> 16) & 1u);   // RNE
    return (unsigned short)(u >> 16);
}
__device__ inline float sigf(float x) { return 1.0f / (1.0f + expf(-x)); }

// device-scope (LLC-coherent) accesses
template <typename T>
__device__ inline T ldg_a(const T* p) {
    return __hip_atomic_load((T*)p, __ATOMIC_RELAXED, __HIP_MEMORY_SCOPE_AGENT);
}
template <typename T>
__device__ inline void stg_a(T* p, T v) {
    __hip_atomic_store(p, v, __ATOMIC_RELAXED, __HIP_MEMORY_SCOPE_AGENT);
}
__device__ inline unsigned int ldu_a(const unsigned int* p) {
    return __hip_atomic_load((unsigned int*)p, __ATOMIC_RELAXED, __HIP_MEMORY_SCOPE_AGENT);
}

// ---- same-XCD L2-coherent ops: sc0 = L1 bypass, served by the XCD-shared L2 ----
__device__ inline unsigned int ld1_sc0(const unsigned int* p) {
    unsigned int v;
    asm volatile("global_load_dword %0, %1, off sc0\n\t"
                 "s_waitcnt vmcnt(0)"
                 : "=v"(v) : "v"(p) : "memory");
    return v;
}
__device__ inline void st1_sc0(unsigned int* p, unsigned int v) {
    asm volatile("global_store_dword %0, %1, off sc0" :: "v"(p), "v"(v) : "memory");
}
// 8 loads at dword stride 64 (= 256 B) from lane base p; all offsets < 4096 (13-bit signed imm)
__device__ inline void row8_sc0(const unsigned int* p, unsigned int v[8]) {
    asm volatile(
        "global_load_dword %0, %[a], off sc0\n\t"
        "global_load_dword %1, %[a], off offset:256 sc0\n\t"
        "global_load_dword %2, %[a], off offset:512 sc0\n\t"
        "global_load_dword %3, %[a], off offset:768 sc0\n\t"
        "global_load_dword %4, %[a], off offset:1024 sc0\n\t"
        "global_load_dword %5, %[a], off offset:1280 sc0\n\t"
        "global_load_dword %6, %[a], off offset:1536 sc0\n\t"
        "global_load_dword %7, %[a], off offset:1792 sc0\n\t"
        "s_waitcnt vmcnt(0)"
        : "=&v"(v[0]), "=&v"(v[1]), "=&v"(v[2]), "=&v"(v[3]),
          "=&v"(v[4]), "=&v"(v[5]), "=&v"(v[6]), "=&v"(v[7])
        : [a]"v"(p)
        : "memory");
}
// 8 strided + 1 extra (wave-uniform column) load
__device__ inline void row9_sc0(const unsigned int* p, const unsigned int* pc,
                                unsigned int v[8], unsigned int& cv) {
    asm volatile(
        "global_load_dword %0, %[a], off sc0\n\t"
        "global_load_dword %1, %[a], off offset:256 sc0\n\t"
        "global_load_dword %2, %[a], off offset:512 sc0\n\t"
        "global_load_dword %3, %[a], off offset:768 sc0\n\t"
        "global_load_dword %4, %[a], off offset:1024 sc0\n\t"
        "global_load_dword %5, %[a], off offset:1280 sc0\n\t"
        "global_load_dword %6, %[a], off offset:1536 sc0\n\t"
        "global_load_dword %7, %[a], off offset:1792 sc0\n\t"
        "global_load_dword %8, %[c], off sc0\n\t"
        "s_waitcnt vmcnt(0)"
        : "=&v"(v[0]), "=&v"(v[1]), "=&v"(v[2]), "=&v"(v[3]),
          "=&v"(v[4]), "=&v"(v[5]), "=&v"(v[6]), "=&v"(v[7]), "=&v"(cv)
        : [a]"v"(p), [c]"v"(pc)
        : "memory");
}
__device__ inline unsigned int get_xcc() {
    // s_getreg_b32 hwreg(HW_REG_XCC_ID=20, offset=0, size=32); mask to 3 bits.
    return __builtin_amdgcn_s_getreg(20 | (0 << 6) | ((32 - 1) << 11)) & 7u;
}

// dual-dtype loads: mode=1 -> bf16 storage, mode=0 -> f32 storage
__device__ inline float4 ld4e(const void* p, size_t eoff, int mode) {
    if (mode) {
        uint2 v = *(const uint2*)((const unsigned short*)p + eoff);
        return make_float4(bf2f(v.x & 0xffffu), bf2f(v.x >> 16),
                           bf2f(v.y & 0xffffu), bf2f(v.y >> 16));
    }
    return *(const float4*)((const float*)p + eoff);
}
__device__ inline float ld1e(const void* p, size_t eoff, int mode) {
    return mode ? bf2f((unsigned int)((const unsigned short*)p)[eoff])
                : ((const float*)p)[eoff];
}

// ---------------- dtype detection ----------------
constexpr int NDET = 4096;
__global__ void detect_kernel(const unsigned int* __restrict__ w, int* __restrict__ cnt) {
    int local = 0;
    for (int i = threadIdx.x; i < NDET; i += 256) {
        unsigned int e = (w[i] >> 7) & 0xffu;
        if (e >= 90u && e <= 140u) local++;
    }
    atomicAdd(cnt, local);
}

// ---------------- precompute GEMM: C[M,N] = gather(A)[M,K] @ B[K,N] + bias ----------------
template<bool GATHER>
__global__ __launch_bounds__(256) void gemm_bias_kernel(
    const void* __restrict__ A, const void* __restrict__ B,
    const void* __restrict__ bias, const int* __restrict__ ids,
    const int* __restrict__ cnt,
    float* __restrict__ C, int M, int N, int K)
{
    const int mode = (*cnt > NDET / 2) ? 1 : 0;
    __shared__ __align__(16) float As[16][68];
    __shared__ __align__(16) float Bs[16][68];
    const int tid = threadIdx.x;
    const int ty = tid >> 4, tx = tid & 15;
    const int m0 = blockIdx.y * 64, n0 = blockIdx.x * 64;
    const int lrow = tid >> 2;
    const int kq   = (tid & 3) * 4;
    const int arow = m0 + lrow;
    const size_t abase = (GATHER ? (size_t)ids[arow] : (size_t)arow) * (size_t)K;
    const int brow = tid >> 4;
    const int bc   = (tid & 15) * 4;
    const int bcol = n0 + bc;
    float acc[4][4] = {};
    for (int k0 = 0; k0 < K; k0 += 16) {
        float4 av = ld4e(A, abase + k0 + kq, mode);
        float4 bv = ld4e(B, (size_t)(k0 + brow) * N + bcol, mode);
        As[kq + 0][lrow] = av.x;
        As[kq + 1][lrow] = av.y;
        As[kq + 2][lrow] = av.z;
        As[kq + 3][lrow] = av.w;
        Bs[brow][bc + 0] = bv.x;
        Bs[brow][bc + 1] = bv.y;
        Bs[brow][bc + 2] = bv.z;
        Bs[brow][bc + 3] = bv.w;
        __syncthreads();
        #pragma unroll
        for (int kk = 0; kk < 16; ++kk) {
            float a[4], bb[4];
            #pragma unroll
            for (int u = 0; u < 4; ++u) a[u] = As[kk][ty * 4 + u];
            #pragma unroll
            for (int v = 0; v < 4; ++v) bb[v] = Bs[kk][tx * 4 + v];
            #pragma unroll
            for (int u = 0; u < 4; ++u)
                #pragma unroll
                for (int v = 0; v < 4; ++v)
                    acc[u][v] = fmaf(a[u], bb[v], acc[u][v]);
        }
        __syncthreads();
    }
    float4 bsv = ld4e(bias, (size_t)(n0 + tx * 4), mode);
    #pragma unroll
    for (int u = 0; u < 4; ++u) {
        float4 o;
        o.x = acc[u][0] + bsv.x; o.y = acc[u][1] + bsv.y;
        o.z = acc[u][2] + bsv.z; o.w = acc[u][3] + bsv.w;
        *(float4*)(C + (size_t)(m0 + ty * 4 + u) * N + n0 + tx * 4) = o;
    }
}

// ---------------- one-time transpose: WT[c][j] = [W_hh|Ww_hh][j][c] (f32 out) ----------------
__global__ __launch_bounds__(256) void transpose_cat_kernel(
    const void* __restrict__ W_hh, const void* __restrict__ Ww_hh,
    const int* __restrict__ cnt, float* __restrict__ out)
{
    const int mode = (*cnt > NDET / 2) ? 1 : 0;
    __shared__ float tile[32][33];
    const int c0 = blockIdx.x * 32;   // [0,3072)
    const int j0 = blockIdx.y * 32;   // [0,512)
    const int tx = threadIdx.x & 31, ty = threadIdx.x >> 5;
    const void* src = (c0 < TH3) ? W_hh : Ww_hh;
    const int cc0 = (c0 < TH3) ? c0 : c0 - TH3;
    #pragma unroll
    for (int dy = 0; dy < 32; dy += 8)
        tile[ty + dy][tx] = ld1e(src, (size_t)(j0 + ty + dy) * TH3 + cc0 + tx, mode);
    __syncthreads();
    #pragma unroll
    for (int dy = 0; dy < 32; dy += 8)
        out[(size_t)(c0 + ty + dy) * HD + j0 + tx] = tile[tx][ty + dy];
}

// ---------------- flag-array barrier among NPART participants (device scope) ----------------
__device__ inline void gbar(int* flags, int b, int k) {
    __atomic_signal_fence(__ATOMIC_SEQ_CST);
    __builtin_amdgcn_s_waitcnt(0);       // drain this wave's stores
    __syncthreads();                     // all waves drained
    if (threadIdx.x < 64) {
        if (threadIdx.x == 0) stg_a(&flags[b], k);
        for (;;) {
            int v = (threadIdx.x < NPART) ? ldg_a(&flags[threadIdx.x]) : k;
            if (__all(v >= k)) break;
            __builtin_amdgcn_s_sleep(1);
        }
    }
    __syncthreads();
    __atomic_signal_fence(__ATOMIC_SEQ_CST);
}

__device__ inline float wave_red(float acc) {
    #pragma unroll
    for (int m = 1; m < 64; m <<= 1) acc += __shfl_xor(acc, m, 64);
    return acc;
}

// ---------------- persistent scan: single-XCD election, L2-coherent dataflow ----------------
// 32 blocks x 16 waves on ONE XCD; wave owns channel ch = b*16 + wid end-to-end.
// Cross-block traffic via sc0 (L1-bypass) ops on the XCD-shared L2 when the
// coherence self-test passes; device-scope (LLC) fallback otherwise. Every poll
// loop has a spin-limit escape to agent-scope loads, so no poll can hang.
__global__ __launch_bounds__(NT) void lattice_scan(
    const float* WT, const void* __restrict__ aW_hh,
    const float* __restrict__ WIb, const float* __restrict__ AWIb,
    const float* __restrict__ WWIb,
    float* hfull, float* c_buf,
    int* flags, int* xcnt, int* elected, int* cohfail, unsigned int* coht,
    const int* __restrict__ cnt,
    const int* __restrict__ gpos, const int* __restrict__ gslot,
    const unsigned char* __restrict__ gmaskb,
    int* __restrict__ meta_hdr, int* __restrict__ meta_rows,
    void* __restrict__ outp, int Km)
{
    __shared__ int sslot, sew, mfmt;

    const int tid  = threadIdx.x;
    const int wid  = tid >> 6;
    const int q    = tid & 63;
    const int mode = (*cnt > NDET / 2) ? 1 : 0;

    // ---- election: first XCD to accumulate NPART arrivals wins ----
    const unsigned int xcd = get_xcc();
    if (tid == 0) {
        int slot = atomicAdd(&xcnt[xcd], 1);
        if (slot == NPART - 1) atomicCAS(elected, 0, (int)xcd + 1);
        sslot = slot;
    }
    __syncthreads();
    const int slot = sslot;
    if (tid == 0) {
        long long t0 = clock64();
        int ew;
        for (;;) {
            ew = ldg_a(elected);
            if (ew != 0) break;
            if (clock64() - t0 > 4000000ll) {   // ~2 ms failsafe
                // only elect an XCD that actually has a full complement
                if (slot == 0 && ldg_a(&xcnt[xcd]) >= NPART)
                    atomicCAS(elected, 0, (int)xcd + 1);
                t0 = clock64();
            }
            __builtin_amdgcn_s_sleep(16);
        }
        sew = ew;
    }
    __syncthreads();
    const int ew = sew;
    if ((int)xcd != ew - 1 || slot >= NPART) return;   // non-participant exits
    const int b  = slot;
    const int ch = b * CHB + wid;                      // own channel (one per wave)

    // ---- one-time init: z weight columns (6 gates x 8 rows/lane), alpha column ----
    float wreg[6][8];
    #pragma unroll
    for (int k = 0; k < 6; ++k)
        #pragma unroll
        for (int i = 0; i < 8; ++i)
            wreg[k][i] = WT[(size_t)(k * HD + ch) * HD + q + 64 * i];
    float aw[8];
    #pragma unroll
    for (int i = 0; i < 8; ++i)
        aw[i] = ld1e(aW_hh, (size_t)(q + 64 * i) * HD + ch, mode);

    if (tid == 0) mfmt = 0;
    __syncthreads();
    {   // mask storage width: nonzero byte at i%4!=0 => u8/bool storage
        int any = 0;
        int tot = SEQ * Km;
        for (int i = tid; i < tot; i += NT)
            if ((i & 3) && gmaskb[i]) any = 1;
        if (any) mfmt = 1;
    }
    __syncthreads();
    const int maskfmt = mfmt;
    const int* gmi = (const int*)gmaskb;

    // ---- one-time metadata precompute: rows packed (p<<2)|sl ----
    if (tid < SPB) {
        int t = b * SPB + tid;
        int nv = 0;
        for (int k = 0; k < Km; ++k) {
            int mv = maskfmt ? (int)gmaskb[t * Km + k] : gmi[t * Km + k];
            if (!mv) continue;
            int p = gpos[t * Km + k], sl = gslot[t * Km + k];
            if (p < 0 || p >= t || sl < 0 || sl >= KWW) continue;
            if (nv < MAXW) { stg_a(&meta_rows[t * MAXW + nv], (p << 2) | sl); nv++; }
        }
        stg_a(&meta_hdr[t], nv);
    }
    // coherence self-test, generation 1: write via sc0, read back after barrier
    if (tid == 0) st1_sc0(&coht[b], MAGIC ^ (unsigned int)b);
    gbar(flags, b, 1);
    if (tid < NPART) {
        unsigned int v = ld1_sc0(&coht[tid]);
        if (v != (MAGIC ^ (unsigned int)tid)) stg_a(cohfail, 1);
    }
    // generation 2: fresh values (guards against a lucky first pass)
    if (tid == 0) st1_sc0(&coht[NPART + b], (MAGIC | 0xA50000u) ^ (unsigned int)b);
    gbar(flags, b, 2);
    if (tid < NPART) {
        unsigned int v = ld1_sc0(&coht[NPART + tid]);
        if (v != ((MAGIC | 0xA50000u) ^ (unsigned int)tid)) stg_a(cohfail, 1);
    }
    gbar(flags, b, 3);
    const bool coh = (ldg_a(cohfail) == 0);

    // meta for step 0: lane l<16 holds row l; all lanes hold hdr
    int nv_c = ldg_a(&meta_hdr[0]);
    int mrow_c = (q < MAXW) ? ldg_a(&meta_rows[q]) : 0;

    const unsigned int* hfu = (const unsigned int*)hfull;
    const unsigned int* cbu = (const unsigned int*)c_buf;
    float c_prev = 0.f;

    for (int t = 0; t < SEQ; ++t) {
        const int nv = nv_c;
        const int mrow = mrow_c;

        // immutable per-step loads (plain, cached; complete under the polls)
        float wi0 = WIb[(size_t)t * TH3 + ch];
        float wi1 = WIb[(size_t)t * TH3 + HD + ch];
        float wi2 = WIb[(size_t)t * TH3 + 2 * HD + ch];
        float wi3 = AWIb[(size_t)t * HD + ch];
        float wwf = 0.f, wwi2 = 0.f, wwg = 0.f;
        if (t > 0 && q < KWW) {
            const float* wr = WWIb + (size_t)((t - 1) * KWW + q) * TH3;
            wwf = wr[ch]; wwi2 = wr[HD + ch]; wwg = wr[2 * HD + ch];
        }
        if (t + 1 < SEQ) {    // prefetch next meta
            nv_c = ldg_a(&meta_hdr[t + 1]);
            mrow_c = (q < MAXW) ? ldg_a(&meta_rows[(size_t)(t + 1) * MAXW + q]) : 0;
        }

        // ===== h_{t-1}: poll straight into GEMV registers =====
        float hv[8];
        if (t > 0) {
            const unsigned int* hp = hfu + (size_t)(t - 1) * HD + q;
            unsigned int v[8];
            bool done = false;
            if (coh) {
                for (int spins = 0; spins < SPIN_ESC; ++spins) {
                    row8_sc0(hp, v);
                    bool ok = true;
                    #pragma unroll
                    for (int i = 0; i < 8; ++i) ok &= (v[i] != SENT);
                    if (__all(ok)) { done = true; break; }
                    __builtin_amdgcn_s_sleep(1);
                }
            }
            if (!done) {
                for (;;) {
                    bool ok = true;
                    #pragma unroll
                    for (int i = 0; i < 8; ++i) { v[i] = ldu_a(hp + 64 * i); ok &= (v[i] != SENT); }
                    if (__all(ok)) break;
                    __builtin_amdgcn_s_sleep(1);
                }
            }
            #pragma unroll
            for (int i = 0; i < 8; ++i) hv[i] = __builtin_bit_cast(float, v[i]);
        } else {
            #pragma unroll
            for (int i = 0; i < 8; ++i) hv[i] = 0.f;
        }

        // ===== word gates first, publish born cells ASAP =====
        float z3 = 0.f, z4 = 0.f, z5 = 0.f;
        #pragma unroll
        for (int i = 0; i < 8; ++i) {
            z3 = fmaf(hv[i], wreg[3][i], z3);
            z4 = fmaf(hv[i], wreg[4][i], z4);
            z5 = fmaf(hv[i], wreg[5][i], z5);
        }
        z3 = wave_red(z3); z4 = wave_red(z4); z5 = wave_red(z5);
        if (t > 0 && q < KWW) {
            float cv = sigf(wwf + z3) * c_prev + sigf(wwi2 + z4) * tanhf(wwg + z5);
            unsigned int* dst = (unsigned int*)&c_buf[(size_t)((t - 1) * KWW + q) * HD + ch];
            if (coh) st1_sc0(dst, __builtin_bit_cast(unsigned int, cv));
            else     stg_a((float*)dst, cv);
        }

        // ===== char gates =====
        float z0 = 0.f, z1 = 0.f, z2 = 0.f;
        #pragma unroll
        for (int i = 0; i < 8; ++i) {
            z0 = fmaf(hv[i], wreg[0][i], z0);
            z1 = fmaf(hv[i], wreg[1][i], z1);
            z2 = fmaf(hv[i], wreg[2][i], z2);
        }
        z0 = wave_red(z0); z1 = wave_red(z1); z2 = wave_red(z2);
        float gi = sigf(z0 + wi0);
        float go = sigf(z1 + wi1);
        float gg = tanhf(z2 + wi2);

        // ===== ending words: per-row poll + alpha + accumulate =====
        float c1;
        if (nv > 0) {
            float wiE = expf(gi);
            float num = wiE * gg, den = wiE;
            for (int vi = 0; vi < nv; ++vi) {
                int e = __shfl(mrow, vi);
                const unsigned int* crow = cbu + (size_t)((e >> 2) * KWW + (e & 3)) * HD;
                unsigned int v[8], cu;
                bool done = false;
                if (coh) {
                    for (int spins = 0; spins < SPIN_ESC; ++spins) {
                        row9_sc0(crow + q, crow + ch, v, cu);
                        bool ok = (cu != SENT);
                        #pragma unroll
                        for (int i = 0; i < 8; ++i) ok &= (v[i] != SENT);
                        if (__all(ok)) { done = true; break; }
                        __builtin_amdgcn_s_sleep(1);
                    }
                }
                if (!done) {
                    for (;;) {
                        cu = ldu_a(crow + ch);
                        bool ok = (cu != SENT);
                        #pragma unroll
                        for (int i = 0; i < 8; ++i) { v[i] = ldu_a(crow + q + 64 * i); ok &= (v[i] != SENT); }
                        if (__all(ok)) break;
                        __builtin_amdgcn_s_sleep(1);
                    }
                }
                float acc = 0.f;
                #pragma unroll
                for (int i = 0; i < 8; ++i)
                    acc = fmaf(__builtin_bit_cast(float, v[i]), aw[i], acc);
                acc = wave_red(acc);
                float wa = expf(sigf(wi3 + acc));
                num = fmaf(wa, __builtin_bit_cast(float, cu), num);
                den += wa;
            }
            c1 = num / den;
        } else {
            c1 = (1.f - gi) * c_prev + gi * gg;
        }
        float h1 = go * tanhf(c1);
        c_prev = c1;

        if (q == 0) {
            unsigned int* hd = (unsigned int*)&hfull[(size_t)t * HD + ch];
            if (coh) st1_sc0(hd, __builtin_bit_cast(unsigned int, h1));
            else     stg_a((float*)hd, h1);
            if (mode) {
                unsigned short* o = (unsigned short*)outp;
                o[(size_t)t * HD + ch] = f2bf(h1);
                o[(size_t)SEQ * HD + (size_t)t * HD + ch] = f2bf(c1);
            } else {
                float* o = (float*)outp;
                o[(size_t)t * HD + ch] = h1;
                o[(size_t)SEQ * HD + (size_t)t * HD + ch] = c1;
            }
        }
        // no barriers: the polls ARE the synchronization
    }
}

extern "C" void kernel_launch(void* const* d_in, const int* in_sizes, int n_in,
                              void* d_out, int out_size, void* d_ws, size_t ws_size,
                              hipStream_t stream) {
    const void* x     = d_in[0];
    const void* W_ih  = d_in[1];
    const void* W_hh  = d_in[2];
    const void* bb    = d_in[3];
    const void* aW_ih = d_in[4];
    const void* aW_hh = d_in[5];
    const void* ab    = d_in[6];
    const void* Ww_ih = d_in[7];
    const void* Ww_hh = d_in[8];
    const void* bw    = d_in[9];
    const void* wemb  = d_in[10];
    const int* wids  = (const int*)d_in[11];
    const int* gpos  = (const int*)d_in[12];
    const int* gslot = (const int*)d_in[13];
    const unsigned char* gmask = (const unsigned char*)d_in[14];

    int Km = in_sizes[12] / SEQ;
    if (Km > 32) Km = 32;
    if (ws_size < WS_END) return;

    char* ws = (char*)d_ws;
    int*   flags = (int*)(ws + WS_FLAGS);
    int*   cnt   = (int*)(ws + WS_CNT);
    int*   xcnt  = (int*)(ws + WS_XCNT);
    int*   elect = (int*)(ws + WS_ELECT);
    int*   cohf  = (int*)(ws + WS_COHF);
    unsigned int* coht = (unsigned int*)(ws + WS_COHT);
    float* c_buf = (float*)(ws + WS_CBUF);
    float* hfull = (float*)(ws + WS_HFULL);
    int*   mhdr  = (int*)(ws + WS_MHDR);
    int*   mrows = (int*)(ws + WS_MROWS);
    float* WIb   = (float*)(ws + WS_WIB);
    float* AWIb  = (float*)(ws + WS_AWIB);
    float* WWIb  = (float*)(ws + WS_WWIB);
    float* WT    = (float*)(ws + WS_WT);

    hipMemsetAsync(ws, 0, WS_ZEROSZ, stream);                         // flags/cnt/election
    hipMemsetAsync(ws + WS_CBUF, 0xFF, WS_FFEND - WS_CBUF, stream);   // sentinel buffers
    detect_kernel<<<1, 256, 0, stream>>>((const unsigned int*)W_ih, cnt);
    transpose_cat_kernel<<<dim3(ZT / 32, HD / 32), 256, 0, stream>>>(
        W_hh, Ww_hh, cnt, WT);
    gemm_bias_kernel<false><<<dim3(TH3 / 64, SEQ / 64), 256, 0, stream>>>(
        x, W_ih, bb, nullptr, cnt, WIb, SEQ, TH3, HD);
    gemm_bias_kernel<false><<<dim3(HD / 64, SEQ / 64), 256, 0, stream>>>(
        x, aW_ih, ab, nullptr, cnt, AWIb, SEQ, HD, HD);
    gemm_bias_kernel<true><<<dim3(TH3 / 64, (SEQ * KWW) / 64), 256, 0, stream>>>(
        wemb, Ww_ih, bw, wids, cnt, WWIb, SEQ * KWW, TH3, HD);
    lattice_scan<<<NLAUNCH, NT, 0, stream>>>(
        WT, aW_hh, WIb, AWIb, WWIb,
        hfull, c_buf, flags, xcnt, elect, cohf, coht, cnt,
        gpos, gslot, gmask, mhdr, mrows, d_out, Km);
}

// Round 6
// 9001.125 us; speedup vs baseline: 2.2240x; 2.2240x over previous
//
#include <hip/hip_runtime.h>

// ---------------- problem constants ----------------
constexpr int SEQ = 2048;
constexpr int HD  = 512;     // H = D = DW
constexpr int TH3 = 1536;    // 3H
constexpr int ZT  = 3072;    // combined [W_hh | Ww_hh] output cols
constexpr int KWW = 3;

constexpr int GRID = 64;     // scan blocks
constexpr int NT   = 512;    // threads/block (8 waves)
constexpr int HB   = HD / GRID;   // 8 h-channels per block (1 per wave)
constexpr int SPB  = SEQ / GRID;  // 32 steps/block metadata precompute
constexpr int MAXW = 16;

constexpr unsigned int SENT = 0xFFFFFFFFu;   // NaN pattern, unreachable by finite gate math

// ws layout (bytes)
// -- zero-memset region --
constexpr size_t WS_FLAGS  = 0;                         // 64 ints (init barrier only)
constexpr size_t WS_CNT    = 1024;                      // dtype-detect counter
constexpr size_t WS_ZEROSZ = 2048;
// -- 0xFF-memset region (sentinel-polled buffers) --
constexpr size_t WS_CBUF   = 2048;                               // SEQ*KWW*HD f32
constexpr size_t WS_HFULL  = WS_CBUF + (size_t)SEQ*KWW*HD*4;     // SEQ*HD f32 (h_t rows)
constexpr size_t WS_FFEND  = WS_HFULL + (size_t)SEQ*HD*4;
// -- plain region --
constexpr size_t WS_MHDR   = ((WS_FFEND + 255)/256)*256;         // SEQ i32
constexpr size_t WS_MROWS  = WS_MHDR + (size_t)SEQ*4;            // SEQ*MAXW i32
constexpr size_t WS_WIB    = WS_MROWS + (size_t)SEQ*MAXW*4;      // SEQ*1536 f32
constexpr size_t WS_AWIB   = WS_WIB  + (size_t)SEQ*TH3*4;        // SEQ*512 f32
constexpr size_t WS_WWIB   = WS_AWIB + (size_t)SEQ*HD*4;         // SEQ*KWW*1536 f32
constexpr size_t WS_WT     = WS_WWIB + (size_t)SEQ*KWW*TH3*4;    // 3072*512 f32 W^T
constexpr size_t WS_END    = WS_WT + (size_t)ZT*HD*4;

__device__ inline float bf2f(unsigned int u) {
    return __builtin_bit_cast(float, u << 16);
}
__device__ inline unsigned short f2bf(float f) {
    unsigned int u = __builtin_bit_cast(unsigned int, f);
    u += 0x7fffu + ((u >> 16) & 1u);   // RNE
    return (unsigned short)(u >> 16);
}
__device__ inline float sigf(float x) { return 1.0f / (1.0f + expf(-x)); }

// LLC-coherent (agent-scope relaxed) accesses: bypass non-coherent L1/L2.
template <typename T>
__device__ inline T ldg_a(const T* p) {
    return __hip_atomic_load((T*)p, __ATOMIC_RELAXED, __HIP_MEMORY_SCOPE_AGENT);
}
template <typename T>
__device__ inline void stg_a(T* p, T v) {
    __hip_atomic_store(p, v, __ATOMIC_RELAXED, __HIP_MEMORY_SCOPE_AGENT);
}
__device__ inline unsigned int ldu_a(const unsigned int* p) {
    return __hip_atomic_load((unsigned int*)p, __ATOMIC_RELAXED, __HIP_MEMORY_SCOPE_AGENT);
}

// ---- batched agent-coherent polls: issue ALL loads, ONE waitcnt (ILP = 1 LLC RT) ----
// 8 loads at 256 B stride (h row: lane q + 64*i dwords)
__device__ inline void poll8(const unsigned int* p, unsigned int v[8]) {
    asm volatile(
        "global_load_dword %0, %[a], off sc0 sc1\n\t"
        "global_load_dword %1, %[a], off offset:256 sc0 sc1\n\t"
        "global_load_dword %2, %[a], off offset:512 sc0 sc1\n\t"
        "global_load_dword %3, %[a], off offset:768 sc0 sc1\n\t"
        "global_load_dword %4, %[a], off offset:1024 sc0 sc1\n\t"
        "global_load_dword %5, %[a], off offset:1280 sc0 sc1\n\t"
        "global_load_dword %6, %[a], off offset:1536 sc0 sc1\n\t"
        "global_load_dword %7, %[a], off offset:1792 sc0 sc1\n\t"
        "s_waitcnt vmcnt(0)"
        : "=&v"(v[0]), "=&v"(v[1]), "=&v"(v[2]), "=&v"(v[3]),
          "=&v"(v[4]), "=&v"(v[5]), "=&v"(v[6]), "=&v"(v[7])
        : [a] "v"(p)
        : "memory");
}
// 16 loads at 128 B stride (cin row: lane l + 32*i dwords, 32-lane group)
__device__ inline void poll16(const unsigned int* p, unsigned int v[16]) {
    asm volatile(
        "global_load_dword %0, %[a], off sc0 sc1\n\t"
        "global_load_dword %1, %[a], off offset:128 sc0 sc1\n\t"
        "global_load_dword %2, %[a], off offset:256 sc0 sc1\n\t"
        "global_load_dword %3, %[a], off offset:384 sc0 sc1\n\t"
        "global_load_dword %4, %[a], off offset:512 sc0 sc1\n\t"
        "global_load_dword %5, %[a], off offset:640 sc0 sc1\n\t"
        "global_load_dword %6, %[a], off offset:768 sc0 sc1\n\t"
        "global_load_dword %7, %[a], off offset:896 sc0 sc1\n\t"
        "global_load_dword %8, %[a], off offset:1024 sc0 sc1\n\t"
        "global_load_dword %9, %[a], off offset:1152 sc0 sc1\n\t"
        "global_load_dword %10, %[a], off offset:1280 sc0 sc1\n\t"
        "global_load_dword %11, %[a], off offset:1408 sc0 sc1\n\t"
        "global_load_dword %12, %[a], off offset:1536 sc0 sc1\n\t"
        "global_load_dword %13, %[a], off offset:1664 sc0 sc1\n\t"
        "global_load_dword %14, %[a], off offset:1792 sc0 sc1\n\t"
        "global_load_dword %15, %[a], off offset:1920 sc0 sc1\n\t"
        "s_waitcnt vmcnt(0)"
        : "=&v"(v[0]),  "=&v"(v[1]),  "=&v"(v[2]),  "=&v"(v[3]),
          "=&v"(v[4]),  "=&v"(v[5]),  "=&v"(v[6]),  "=&v"(v[7]),
          "=&v"(v[8]),  "=&v"(v[9]),  "=&v"(v[10]), "=&v"(v[11]),
          "=&v"(v[12]), "=&v"(v[13]), "=&v"(v[14]), "=&v"(v[15])
        : [a] "v"(p)
        : "memory");
}

// dual-dtype loads: mode=1 -> bf16 storage, mode=0 -> f32 storage
__device__ inline float4 ld4e(const void* p, size_t eoff, int mode) {
    if (mode) {
        uint2 v = *(const uint2*)((const unsigned short*)p + eoff);
        return make_float4(bf2f(v.x & 0xffffu), bf2f(v.x >> 16),
                           bf2f(v.y & 0xffffu), bf2f(v.y >> 16));
    }
    return *(const float4*)((const float*)p + eoff);
}
__device__ inline float ld1e(const void* p, size_t eoff, int mode) {
    return mode ? bf2f((unsigned int)((const unsigned short*)p)[eoff])
                : ((const float*)p)[eoff];
}

// ---------------- dtype detection ----------------
constexpr int NDET = 4096;
__global__ void detect_kernel(const unsigned int* __restrict__ w, int* __restrict__ cnt) {
    int local = 0;
    for (int i = threadIdx.x; i < NDET; i += 256) {
        unsigned int e = (w[i] >> 7) & 0xffu;
        if (e >= 90u && e <= 140u) local++;
    }
    atomicAdd(cnt, local);
}

// ---------------- precompute GEMM: C[M,N] = gather(A)[M,K] @ B[K,N] + bias ----------------
template<bool GATHER>
__global__ __launch_bounds__(256) void gemm_bias_kernel(
    const void* __restrict__ A, const void* __restrict__ B,
    const void* __restrict__ bias, const int* __restrict__ ids,
    const int* __restrict__ cnt,
    float* __restrict__ C, int M, int N, int K)
{
    const int mode = (*cnt > NDET / 2) ? 1 : 0;
    __shared__ __align__(16) float As[16][68];
    __shared__ __align__(16) float Bs[16][68];
    const int tid = threadIdx.x;
    const int ty = tid >> 4, tx = tid & 15;
    const int m0 = blockIdx.y * 64, n0 = blockIdx.x * 64;
    const int lrow = tid >> 2;
    const int kq   = (tid & 3) * 4;
    const int arow = m0 + lrow;
    const size_t abase = (GATHER ? (size_t)ids[arow] : (size_t)arow) * (size_t)K;
    const int brow = tid >> 4;
    const int bc   = (tid & 15) * 4;
    const int bcol = n0 + bc;
    float acc[4][4] = {};
    for (int k0 = 0; k0 < K; k0 += 16) {
        float4 av = ld4e(A, abase + k0 + kq, mode);
        float4 bv = ld4e(B, (size_t)(k0 + brow) * N + bcol, mode);
        As[kq + 0][lrow] = av.x;
        As[kq + 1][lrow] = av.y;
        As[kq + 2][lrow] = av.z;
        As[kq + 3][lrow] = av.w;
        Bs[brow][bc + 0] = bv.x;
        Bs[brow][bc + 1] = bv.y;
        Bs[brow][bc + 2] = bv.z;
        Bs[brow][bc + 3] = bv.w;
        __syncthreads();
        #pragma unroll
        for (int kk = 0; kk < 16; ++kk) {
            float a[4], bb[4];
            #pragma unroll
            for (int u = 0; u < 4; ++u) a[u] = As[kk][ty * 4 + u];
            #pragma unroll
            for (int v = 0; v < 4; ++v) bb[v] = Bs[kk][tx * 4 + v];
            #pragma unroll
            for (int u = 0; u < 4; ++u)
                #pragma unroll
                for (int v = 0; v < 4; ++v)
                    acc[u][v] = fmaf(a[u], bb[v], acc[u][v]);
        }
        __syncthreads();
    }
    float4 bsv = ld4e(bias, (size_t)(n0 + tx * 4), mode);
    #pragma unroll
    for (int u = 0; u < 4; ++u) {
        float4 o;
        o.x = acc[u][0] + bsv.x; o.y = acc[u][1] + bsv.y;
        o.z = acc[u][2] + bsv.z; o.w = acc[u][3] + bsv.w;
        *(float4*)(C + (size_t)(m0 + ty * 4 + u) * N + n0 + tx * 4) = o;
    }
}

// ---------------- one-time transpose: WT[c][j] = [W_hh|Ww_hh][j][c] (f32 out) ----------------
__global__ __launch_bounds__(256) void transpose_cat_kernel(
    const void* __restrict__ W_hh, const void* __restrict__ Ww_hh,
    const int* __restrict__ cnt, float* __restrict__ out)
{
    const int mode = (*cnt > NDET / 2) ? 1 : 0;
    __shared__ float tile[32][33];
    const int c0 = blockIdx.x * 32;   // [0,3072)
    const int j0 = blockIdx.y * 32;   // [0,512)
    const int tx = threadIdx.x & 31, ty = threadIdx.x >> 5;
    const void* src = (c0 < TH3) ? W_hh : Ww_hh;
    const int cc0 = (c0 < TH3) ? c0 : c0 - TH3;
    #pragma unroll
    for (int dy = 0; dy < 32; dy += 8)
        tile[ty + dy][tx] = ld1e(src, (size_t)(j0 + ty + dy) * TH3 + cc0 + tx, mode);
    __syncthreads();
    #pragma unroll
    for (int dy = 0; dy < 32; dy += 8)
        out[(size_t)(c0 + ty + dy) * HD + j0 + tx] = tile[tx][ty + dy];
}

// ---------------- flag-array barrier (init only) ----------------
__device__ inline void gbar(int* flags, int b, int k) {
    __atomic_signal_fence(__ATOMIC_SEQ_CST);
    __builtin_amdgcn_s_waitcnt(0);       // drain this wave's stores
    __syncthreads();                     // all waves drained
    if (threadIdx.x < 64) {
        if (threadIdx.x == 0) stg_a(&flags[b], k);
        for (;;) {
            int v = ldg_a(&flags[threadIdx.x]);
            if (__all(v >= k)) break;
            __builtin_amdgcn_s_sleep(1);
        }
    }
    __syncthreads();
    __atomic_signal_fence(__ATOMIC_SEQ_CST);
}

__device__ inline float wave_red(float acc) {
    #pragma unroll
    for (int m = 1; m < 64; m <<= 1) acc += __shfl_xor(acc, m, 64);
    return acc;
}

// ---------------- persistent scan: per-wave channel ownership, batched polls ----------------
__global__ __launch_bounds__(NT, 1) void lattice_scan(
    const float* WT, const void* __restrict__ aW_hh,
    const float* __restrict__ WIb, const float* __restrict__ AWIb,
    const float* __restrict__ WWIb,
    float* hfull, float* c_buf, int* __restrict__ flags,
    const int* __restrict__ cnt,
    const int* __restrict__ gpos, const int* __restrict__ gslot,
    const unsigned char* __restrict__ gmaskb,
    int* __restrict__ meta_hdr, int* __restrict__ meta_rows,
    void* __restrict__ outp, int Km)
{
    __shared__ __align__(16) float cinS[2][MAXW][HD];   // double-buffered cin rows (64 KB)
    __shared__ int mh_l[2], mr_l[2][MAXW];
    __shared__ int mfmt;

    const int b    = blockIdx.x;
    const int tid  = threadIdx.x;
    const int wid  = tid >> 6;
    const int q    = tid & 63;
    const int mode = (*cnt > NDET / 2) ? 1 : 0;
    const int hb0  = b * HB;
    const int ch   = hb0 + wid;       // own h-channel (one per wave)

    // ---- one-time init: z weight columns (6 gates x 8 rows/lane), alpha column ----
    float wreg[6][8];
    #pragma unroll
    for (int k = 0; k < 6; ++k)
        #pragma unroll
        for (int i = 0; i < 8; ++i)
            wreg[k][i] = WT[(size_t)(k * HD + ch) * HD + q + 64 * i];
    float aw[8];
    #pragma unroll
    for (int i = 0; i < 8; ++i)
        aw[i] = ld1e(aW_hh, (size_t)(q + 64 * i) * HD + ch, mode);

    if (tid == 0) mfmt = 0;
    __syncthreads();
    {   // mask storage width: nonzero byte at i%4!=0 => u8/bool storage
        int any = 0;
        int tot = SEQ * Km;
        for (int i = tid; i < tot; i += NT)
            if ((i & 3) && gmaskb[i]) any = 1;
        if (any) mfmt = 1;
    }
    __syncthreads();
    const int maskfmt = mfmt;
    const int* gmi = (const int*)gmaskb;

    // ---- one-time metadata precompute: rows packed (p<<2)|sl ----
    if (tid < SPB) {
        int t = b * SPB + tid;
        int nv = 0;
        for (int k = 0; k < Km; ++k) {
            int mv = maskfmt ? (int)gmaskb[t * Km + k] : gmi[t * Km + k];
            if (!mv) continue;
            int p = gpos[t * Km + k], sl = gslot[t * Km + k];
            if (p < 0 || p >= t || sl < 0 || sl >= KWW) continue;
            if (nv < MAXW) { stg_a(&meta_rows[t * MAXW + nv], (p << 2) | sl); nv++; }
        }
        stg_a(&meta_hdr[t], nv);
    }
    gbar(flags, b, 1);   // publish metadata (only global barrier in the kernel)

    // meta for step 0 (plain loads: immutable after barrier)
    if (tid == 0) mh_l[0] = ldg_a(&meta_hdr[0]);
    if (tid < MAXW) mr_l[0][tid] = ldg_a(&meta_rows[tid]);
    __syncthreads();

    const unsigned int* hfu = (const unsigned int*)hfull;
    const unsigned int* cbu = (const unsigned int*)c_buf;
    float c_prev = 0.f;                 // own channel's c_{t-1}, live in all lanes

    for (int t = 0; t < SEQ; ++t) {
        const int par = t & 1;
        const int nv = mh_l[par];
        bool anyl2 = false;
        for (int vi = 0; vi < nv; ++vi)
            if ((mr_l[par][vi] >> 2) == t - 1) anyl2 = true;

        // ===== phase 1 =====
        // uniform immutable loads for own channel (broadcast addresses)
        float wi0 = WIb[(size_t)t * TH3 + ch];
        float wi1 = WIb[(size_t)t * TH3 + HD + ch];
        float wi2 = WIb[(size_t)t * TH3 + 2 * HD + ch];
        float wi3 = AWIb[(size_t)t * HD + ch];
        float wwf = 0.f, wwi = 0.f, wwg = 0.f;
        if (t > 0 && q < KWW) {
            const float* wr = WWIb + (size_t)((t - 1) * KWW + q) * TH3;
            wwf = wr[ch]; wwi = wr[HD + ch]; wwg = wr[2 * HD + ch];
        }
        // prefetch next meta
        if (t + 1 < SEQ) {
            if (tid == 0) mh_l[par ^ 1] = ldg_a(&meta_hdr[t + 1]);
            if (tid < MAXW)
                mr_l[par ^ 1][tid] = ldg_a(&meta_rows[(size_t)(t + 1) * MAXW + tid]);
        }

        // far cin rows (p <= t-2): batched sentinel-poll into cinS[par]
        {
            int g = tid >> 5, l = tid & 31;
            bool act = false;
            const unsigned int* src = nullptr;
            if (g < nv) {
                int e = mr_l[par][g], p = e >> 2, sl = e & 3;
                if (p <= t - 2)
                    { act = true; src = cbu + (size_t)(p * KWW + sl) * HD + l; }
            }
            unsigned int v[16];
            for (;;) {
                bool ok = true;
                if (act) {
                    poll16(src, v);
                    #pragma unroll
                    for (int i = 0; i < 16; ++i) ok &= (v[i] != SENT);
                }
                if (__all(ok)) break;
                __builtin_amdgcn_s_sleep(1);
            }
            if (act) {
                #pragma unroll
                for (int i = 0; i < 16; ++i)
                    cinS[par][g][l + 32 * i] = __builtin_bit_cast(float, v[i]);
            }
        }

        // h_{t-1}: batched poll straight into GEMV registers
        float hv[8];
        if (t > 0) {
            const unsigned int* hp = hfu + (size_t)(t - 1) * HD + q;
            unsigned int v[8];
            for (;;) {
                poll8(hp, v);
                bool ok = true;
                #pragma unroll
                for (int i = 0; i < 8; ++i) ok &= (v[i] != SENT);
                if (__all(ok)) break;
                __builtin_amdgcn_s_sleep(1);
            }
            #pragma unroll
            for (int i = 0; i < 8; ++i) hv[i] = __builtin_bit_cast(float, v[i]);
        } else {
            #pragma unroll
            for (int i = 0; i < 8; ++i) hv[i] = 0.f;
        }

        // ===== word gates first: publish born cells ASAP =====
        float z3 = 0.f, z4 = 0.f, z5 = 0.f;
        #pragma unroll
        for (int i = 0; i < 8; ++i) {
            z3 = fmaf(hv[i], wreg[3][i], z3);
            z4 = fmaf(hv[i], wreg[4][i], z4);
            z5 = fmaf(hv[i], wreg[5][i], z5);
        }
        z3 = wave_red(z3); z4 = wave_red(z4); z5 = wave_red(z5);
        if (t > 0 && q < KWW) {
            float cv = sigf(wwf + z3) * c_prev + sigf(wwi + z4) * tanhf(wwg + z5);
            stg_a(&c_buf[(size_t)((t - 1) * KWW + q) * HD + ch], cv);
        }

        // char gates
        float z0 = 0.f, z1 = 0.f, z2 = 0.f;
        #pragma unroll
        for (int i = 0; i < 8; ++i) {
            z0 = fmaf(hv[i], wreg[0][i], z0);
            z1 = fmaf(hv[i], wreg[1][i], z1);
            z2 = fmaf(hv[i], wreg[2][i], z2);
        }
        z0 = wave_red(z0); z1 = wave_red(z1); z2 = wave_red(z2);

        // near cin rows (p == t-1, len-2 words): batched poll of born stores
        if (anyl2) {
            int g = tid >> 5, l = tid & 31;
            bool act = false;
            const unsigned int* src = nullptr;
            if (g < nv) {
                int e = mr_l[par][g], p = e >> 2, sl = e & 3;
                if (p == t - 1)
                    { act = true; src = cbu + (size_t)(p * KWW + sl) * HD + l; }
            }
            unsigned int v[16];
            for (;;) {
                bool ok = true;
                if (act) {
                    poll16(src, v);
                    #pragma unroll
                    for (int i = 0; i < 16; ++i) ok &= (v[i] != SENT);
                }
                if (__all(ok)) break;
                __builtin_amdgcn_s_sleep(1);
            }
            if (act) {
                #pragma unroll
                for (int i = 0; i < 16; ++i)
                    cinS[par][g][l + 32 * i] = __builtin_bit_cast(float, v[i]);
            }
        }

        __syncthreads();   // cinS[par] complete; the ONLY in-block sync per step

        // ===== phase 2: alpha + merge, redundant on all lanes of own wave =====
        float gi = sigf(z0 + wi0);
        float go = sigf(z1 + wi1);
        float gg = tanhf(z2 + wi2);
        float c1;
        if (nv > 0) {
            float wiE = expf(gi);
            float num = wiE * gg, den = wiE;
            for (int vi = 0; vi < nv; ++vi) {
                float acc = 0.f;
                #pragma unroll
                for (int i = 0; i < 8; ++i)
                    acc += cinS[par][vi][q + 64 * i] * aw[i];
                acc = wave_red(acc);
                float wa = expf(sigf(wi3 + acc));
                num += wa * cinS[par][vi][ch];     // broadcast LDS read
                den += wa;
            }
            c1 = num / den;
        } else {
            c1 = (1.f - gi) * c_prev + gi * gg;
        }
        float h1 = go * tanhf(c1);
        c_prev = c1;
        if (q == 0) {
            stg_a(&hfull[(size_t)t * HD + ch], h1);
            if (mode) {
                unsigned short* o = (unsigned short*)outp;
                o[(size_t)t * HD + ch] = f2bf(h1);
                o[(size_t)SEQ * HD + (size_t)t * HD + ch] = f2bf(c1);
            } else {
                float* o = (float*)outp;
                o[(size_t)t * HD + ch] = h1;
                o[(size_t)SEQ * HD + (size_t)t * HD + ch] = c1;
            }
        }
        // no end-of-step sync: next step's polls + double-buffered cinS enforce order
    }
}

extern "C" void kernel_launch(void* const* d_in, const int* in_sizes, int n_in,
                              void* d_out, int out_size, void* d_ws, size_t ws_size,
                              hipStream_t stream) {
    const void* x     = d_in[0];
    const void* W_ih  = d_in[1];
    const void* W_hh  = d_in[2];
    const void* bb    = d_in[3];
    const void* aW_ih = d_in[4];
    const void* aW_hh = d_in[5];
    const void* ab    = d_in[6];
    const void* Ww_ih = d_in[7];
    const void* Ww_hh = d_in[8];
    const void* bw    = d_in[9];
    const void* wemb  = d_in[10];
    const int* wids  = (const int*)d_in[11];
    const int* gpos  = (const int*)d_in[12];
    const int* gslot = (const int*)d_in[13];
    const unsigned char* gmask = (const unsigned char*)d_in[14];

    int Km = in_sizes[12] / SEQ;
    if (Km > 32) Km = 32;
    if (ws_size < WS_END) return;

    char* ws = (char*)d_ws;
    int*   flags = (int*)(ws + WS_FLAGS);
    int*   cnt   = (int*)(ws + WS_CNT);
    float* c_buf = (float*)(ws + WS_CBUF);
    float* hfull = (float*)(ws + WS_HFULL);
    int*   mhdr  = (int*)(ws + WS_MHDR);
    int*   mrows = (int*)(ws + WS_MROWS);
    float* WIb   = (float*)(ws + WS_WIB);
    float* AWIb  = (float*)(ws + WS_AWIB);
    float* WWIb  = (float*)(ws + WS_WWIB);
    float* WT    = (float*)(ws + WS_WT);

    hipMemsetAsync(ws, 0, WS_ZEROSZ, stream);                         // flags/cnt
    hipMemsetAsync(ws + WS_CBUF, 0xFF, WS_FFEND - WS_CBUF, stream);   // sentinel buffers
    detect_kernel<<<1, 256, 0, stream>>>((const unsigned int*)W_ih, cnt);
    transpose_cat_kernel<<<dim3(ZT / 32, HD / 32), 256, 0, stream>>>(
        W_hh, Ww_hh, cnt, WT);
    gemm_bias_kernel<false><<<dim3(TH3 / 64, SEQ / 64), 256, 0, stream>>>(
        x, W_ih, bb, nullptr, cnt, WIb, SEQ, TH3, HD);
    gemm_bias_kernel<false><<<dim3(HD / 64, SEQ / 64), 256, 0, stream>>>(
        x, aW_ih, ab, nullptr, cnt, AWIb, SEQ, HD, HD);
    gemm_bias_kernel<true><<<dim3(TH3 / 64, (SEQ * KWW) / 64), 256, 0, stream>>>(
        wemb, Ww_ih, bw, wids, cnt, WWIb, SEQ * KWW, TH3, HD);
    lattice_scan<<<GRID, NT, 0, stream>>>(
        WT, aW_hh, WIb, AWIb, WWIb,
        hfull, c_buf, flags, cnt,
        gpos, gslot, gmask, mhdr, mrows, d_out, Km);
}

// Round 8
// 8334.407 us; speedup vs baseline: 2.4020x; 1.0800x over previous
//
#include <hip/hip_runtime.h>

// ---------------- problem constants ----------------
constexpr int SEQ = 2048;
constexpr int HD  = 512;     // H = D = DW
constexpr int TH3 = 1536;    // 3H
constexpr int ZT  = 3072;    // combined [W_hh | Ww_hh] output cols
constexpr int KWW = 3;

constexpr int GRID = 64;     // scan blocks
constexpr int NT   = 512;    // threads/block (8 waves)
constexpr int HB   = HD / GRID;   // 8 h-channels per block (1 per wave)
constexpr int SPB  = SEQ / GRID;  // 32 steps/block metadata precompute
constexpr int MAXW = 16;
constexpr int FMAX = 4;      // far cin rows kept in registers per pass

constexpr unsigned int SENT = 0xFFFFFFFFu;   // NaN pattern, unreachable by finite gate math

// ws layout (bytes)
// -- zero-memset region --
constexpr size_t WS_FLAGS  = 0;                         // 64 ints (init barrier only)
constexpr size_t WS_CNT    = 1024;                      // dtype-detect counter
constexpr size_t WS_ZEROSZ = 2048;
// -- 0xFF-memset region (sentinel-polled buffers) --
constexpr size_t WS_CBUF   = 2048;                               // SEQ*KWW*HD f32
constexpr size_t WS_HFULL  = WS_CBUF + (size_t)SEQ*KWW*HD*4;     // SEQ*HD f32 (h_t rows)
constexpr size_t WS_FFEND  = WS_HFULL + (size_t)SEQ*HD*4;
// -- plain region --
constexpr size_t WS_MHDR   = ((WS_FFEND + 255)/256)*256;         // SEQ i32
constexpr size_t WS_MROWS  = WS_MHDR + (size_t)SEQ*4;            // SEQ*MAXW i32
constexpr size_t WS_WIB    = WS_MROWS + (size_t)SEQ*MAXW*4;      // SEQ*1536 f32
constexpr size_t WS_AWIB   = WS_WIB  + (size_t)SEQ*TH3*4;        // SEQ*512 f32
constexpr size_t WS_WWIB   = WS_AWIB + (size_t)SEQ*HD*4;         // SEQ*KWW*1536 f32
constexpr size_t WS_WT     = WS_WWIB + (size_t)SEQ*KWW*TH3*4;    // 3072*512 f32 W^T
constexpr size_t WS_END    = WS_WT + (size_t)ZT*HD*4;

__device__ inline float bf2f(unsigned int u) {
    return __builtin_bit_cast(float, u << 16);
}
__device__ inline unsigned short f2bf(float f) {
    unsigned int u = __builtin_bit_cast(unsigned int, f);
    u += 0x7fffu + ((u >> 16) & 1u);   // RNE
    return (unsigned short)(u >> 16);
}
__device__ inline float sigf(float x) { return 1.0f / (1.0f + expf(-x)); }

// LLC-coherent (agent-scope relaxed) accesses: bypass non-coherent L1/L2.
template <typename T>
__device__ inline T ldg_a(const T* p) {
    return __hip_atomic_load((T*)p, __ATOMIC_RELAXED, __HIP_MEMORY_SCOPE_AGENT);
}
template <typename T>
__device__ inline void stg_a(T* p, T v) {
    __hip_atomic_store(p, v, __ATOMIC_RELAXED, __HIP_MEMORY_SCOPE_AGENT);
}
__device__ inline unsigned int ldu_a(const unsigned int* p) {
    return __hip_atomic_load((unsigned int*)p, __ATOMIC_RELAXED, __HIP_MEMORY_SCOPE_AGENT);
}

// one sentinel pass over an 8x64-strided row; returns "all ready"
__device__ inline bool ld_row8(const unsigned int* base, unsigned int ru[8]) {
    bool ok = true;
    #pragma unroll
    for (int i = 0; i < 8; ++i) {
        ru[i] = ldu_a(base + 64 * i);
        ok &= (ru[i] != SENT);
    }
    return ok;
}

// dual-dtype loads: mode=1 -> bf16 storage, mode=0 -> f32 storage
__device__ inline float4 ld4e(const void* p, size_t eoff, int mode) {
    if (mode) {
        uint2 v = *(const uint2*)((const unsigned short*)p + eoff);
        return make_float4(bf2f(v.x & 0xffffu), bf2f(v.x >> 16),
                           bf2f(v.y & 0xffffu), bf2f(v.y >> 16));
    }
    return *(const float4*)((const float*)p + eoff);
}
__device__ inline float ld1e(const void* p, size_t eoff, int mode) {
    return mode ? bf2f((unsigned int)((const unsigned short*)p)[eoff])
                : ((const float*)p)[eoff];
}

// ---------------- dtype detection ----------------
constexpr int NDET = 4096;
__global__ void detect_kernel(const unsigned int* __restrict__ w, int* __restrict__ cnt) {
    int local = 0;
    for (int i = threadIdx.x; i < NDET; i += 256) {
        unsigned int e = (w[i] >> 7) & 0xffu;
        if (e >= 90u && e <= 140u) local++;
    }
    atomicAdd(cnt, local);
}

// ---------------- precompute GEMM: C[M,N] = gather(A)[M,K] @ B[K,N] + bias ----------------
template<bool GATHER>
__global__ __launch_bounds__(256) void gemm_bias_kernel(
    const void* __restrict__ A, const void* __restrict__ B,
    const void* __restrict__ bias, const int* __restrict__ ids,
    const int* __restrict__ cnt,
    float* __restrict__ C, int M, int N, int K)
{
    const int mode = (*cnt > NDET / 2) ? 1 : 0;
    __shared__ __align__(16) float As[16][68];
    __shared__ __align__(16) float Bs[16][68];
    const int tid = threadIdx.x;
    const int ty = tid >> 4, tx = tid & 15;
    const int m0 = blockIdx.y * 64, n0 = blockIdx.x * 64;
    const int lrow = tid >> 2;
    const int kq   = (tid & 3) * 4;
    const int arow = m0 + lrow;
    const size_t abase = (GATHER ? (size_t)ids[arow] : (size_t)arow) * (size_t)K;
    const int brow = tid >> 4;
    const int bc   = (tid & 15) * 4;
    const int bcol = n0 + bc;
    float acc[4][4] = {};
    for (int k0 = 0; k0 < K; k0 += 16) {
        float4 av = ld4e(A, abase + k0 + kq, mode);
        float4 bv = ld4e(B, (size_t)(k0 + brow) * N + bcol, mode);
        As[kq + 0][lrow] = av.x;
        As[kq + 1][lrow] = av.y;
        As[kq + 2][lrow] = av.z;
        As[kq + 3][lrow] = av.w;
        Bs[brow][bc + 0] = bv.x;
        Bs[brow][bc + 1] = bv.y;
        Bs[brow][bc + 2] = bv.z;
        Bs[brow][bc + 3] = bv.w;
        __syncthreads();
        #pragma unroll
        for (int kk = 0; kk < 16; ++kk) {
            float a[4], bb[4];
            #pragma unroll
            for (int u = 0; u < 4; ++u) a[u] = As[kk][ty * 4 + u];
            #pragma unroll
            for (int v = 0; v < 4; ++v) bb[v] = Bs[kk][tx * 4 + v];
            #pragma unroll
            for (int u = 0; u < 4; ++u)
                #pragma unroll
                for (int v = 0; v < 4; ++v)
                    acc[u][v] = fmaf(a[u], bb[v], acc[u][v]);
        }
        __syncthreads();
    }
    float4 bsv = ld4e(bias, (size_t)(n0 + tx * 4), mode);
    #pragma unroll
    for (int u = 0; u < 4; ++u) {
        float4 o;
        o.x = acc[u][0] + bsv.x; o.y = acc[u][1] + bsv.y;
        o.z = acc[u][2] + bsv.z; o.w = acc[u][3] + bsv.w;
        *(float4*)(C + (size_t)(m0 + ty * 4 + u) * N + n0 + tx * 4) = o;
    }
}

// ---------------- one-time transpose: WT[c][j] = [W_hh|Ww_hh][j][c] (f32 out) ----------------
__global__ __launch_bounds__(256) void transpose_cat_kernel(
    const void* __restrict__ W_hh, const void* __restrict__ Ww_hh,
    const int* __restrict__ cnt, float* __restrict__ out)
{
    const int mode = (*cnt > NDET / 2) ? 1 : 0;
    __shared__ float tile[32][33];
    const int c0 = blockIdx.x * 32;   // [0,3072)
    const int j0 = blockIdx.y * 32;   // [0,512)
    const int tx = threadIdx.x & 31, ty = threadIdx.x >> 5;
    const void* src = (c0 < TH3) ? W_hh : Ww_hh;
    const int cc0 = (c0 < TH3) ? c0 : c0 - TH3;
    #pragma unroll
    for (int dy = 0; dy < 32; dy += 8)
        tile[ty + dy][tx] = ld1e(src, (size_t)(j0 + ty + dy) * TH3 + cc0 + tx, mode);
    __syncthreads();
    #pragma unroll
    for (int dy = 0; dy < 32; dy += 8)
        out[(size_t)(c0 + ty + dy) * HD + j0 + tx] = tile[tx][ty + dy];
}

// ---------------- flag-array barrier (init only) ----------------
__device__ inline void gbar(int* flags, int b, int k) {
    __atomic_signal_fence(__ATOMIC_SEQ_CST);
    __builtin_amdgcn_s_waitcnt(0);       // drain this wave's stores
    __syncthreads();                     // all waves drained
    if (threadIdx.x < 64) {
        if (threadIdx.x == 0) stg_a(&flags[b], k);
        for (;;) {
            int v = ldg_a(&flags[threadIdx.x]);
            if (__all(v >= k)) break;
            __builtin_amdgcn_s_sleep(1);
        }
    }
    __syncthreads();
    __atomic_signal_fence(__ATOMIC_SEQ_CST);
}

__device__ inline float wave_red(float acc) {
    #pragma unroll
    for (int m = 1; m < 64; m <<= 1) acc += __shfl_xor(acc, m, 64);
    return acc;
}

// ---------------- persistent scan: fully wave-independent, register dataflow ----------------
// Wave owns channel ch = b*8 + wid end-to-end. NO per-step __syncthreads, NO LDS
// staging: cin rows live in registers; the combined sentinel poll keeps the h row
// and all (far) cin rows in flight together -> one LLC round trip per step.
__global__ __launch_bounds__(NT, 1) void lattice_scan(
    const float* WT, const void* __restrict__ aW_hh,
    const float* __restrict__ WIb, const float* __restrict__ AWIb,
    const float* __restrict__ WWIb,
    float* hfull, float* c_buf, int* __restrict__ flags,
    const int* __restrict__ cnt,
    const int* __restrict__ gpos, const int* __restrict__ gslot,
    const unsigned char* __restrict__ gmaskb,
    int* __restrict__ meta_hdr, int* __restrict__ meta_rows,
    void* __restrict__ outp, int Km)
{
    __shared__ int mfmt;

    const int b    = blockIdx.x;
    const int tid  = threadIdx.x;
    const int wid  = tid >> 6;
    const int q    = tid & 63;
    const int mode = (*cnt > NDET / 2) ? 1 : 0;
    const int ch   = b * HB + wid;    // own h-channel (one per wave)
    const int chHi = ch >> 6;         // wave-uniform reg index of cin[ch]
    const int chLo = ch & 63;         // lane holding cin[ch]

    // ---- one-time init: z weight columns (6 gates x 8 rows/lane), alpha column ----
    float wreg[6][8];
    #pragma unroll
    for (int k = 0; k < 6; ++k)
        #pragma unroll
        for (int i = 0; i < 8; ++i)
            wreg[k][i] = WT[(size_t)(k * HD + ch) * HD + q + 64 * i];
    float aw[8];
    #pragma unroll
    for (int i = 0; i < 8; ++i)
        aw[i] = ld1e(aW_hh, (size_t)(q + 64 * i) * HD + ch, mode);

    if (tid == 0) mfmt = 0;
    __syncthreads();
    {   // mask storage width: nonzero byte at i%4!=0 => u8/bool storage
        int any = 0;
        int tot = SEQ * Km;
        for (int i = tid; i < tot; i += NT)
            if ((i & 3) && gmaskb[i]) any = 1;
        if (any) mfmt = 1;
    }
    __syncthreads();
    const int maskfmt = mfmt;
    const int* gmi = (const int*)gmaskb;

    // ---- one-time metadata precompute: rows packed (p<<2)|sl ----
    if (tid < SPB) {
        int t = b * SPB + tid;
        int nv = 0;
        for (int k = 0; k < Km; ++k) {
            int mv = maskfmt ? (int)gmaskb[t * Km + k] : gmi[t * Km + k];
            if (!mv) continue;
            int p = gpos[t * Km + k], sl = gslot[t * Km + k];
            if (p < 0 || p >= t || sl < 0 || sl >= KWW) continue;
            if (nv < MAXW) { stg_a(&meta_rows[t * MAXW + nv], (p << 2) | sl); nv++; }
        }
        stg_a(&meta_hdr[t], nv);
    }
    gbar(flags, b, 1);   // publish metadata (only global barrier in the kernel)

    // per-wave meta (plain loads: immutable after barrier, cacheable)
    int nv_c = meta_hdr[0];
    int mrow_c = (q < MAXW) ? meta_rows[q] : 0;

    const unsigned int* hfu = (const unsigned int*)hfull;
    const unsigned int* cbu = (const unsigned int*)c_buf;
    float c_prev = 0.f;                 // own channel's c_{t-1}, live in all lanes

    for (int t = 0; t < SEQ; ++t) {
        const int nv = nv_c;
        const int mrow = mrow_c;

        // immutable per-step loads (broadcast addresses; overlap the poll)
        float wi0 = WIb[(size_t)t * TH3 + ch];
        float wi1 = WIb[(size_t)t * TH3 + HD + ch];
        float wi2 = WIb[(size_t)t * TH3 + 2 * HD + ch];
        float wi3 = AWIb[(size_t)t * HD + ch];
        float wwf = 0.f, wwi = 0.f, wwg = 0.f;
        if (t > 0 && q < KWW) {
            const float* wr = WWIb + (size_t)((t - 1) * KWW + q) * TH3;
            wwf = wr[ch]; wwi = wr[HD + ch]; wwg = wr[2 * HD + ch];
        }
        if (t + 1 < SEQ) {   // prefetch next meta (plain cached loads)
            nv_c = meta_hdr[t + 1];
            mrow_c = (q < MAXW) ? meta_rows[(size_t)(t + 1) * MAXW + q] : 0;
        }

        // ---- classify ending-word rows: far (p<=t-2) -> f0..f3 (+overflow), near (p==t-1) -> n0..n2
        const unsigned int *f0 = nullptr, *f1 = nullptr, *f2 = nullptr, *f3 = nullptr;
        const unsigned int *n0 = nullptr, *n1 = nullptr, *n2 = nullptr;
        int nf = 0, nn = 0;
        for (int vi = 0; vi < nv; ++vi) {
            int e = __shfl(mrow, vi);
            int p = e >> 2, sl = e & 3;
            const unsigned int* base = cbu + (size_t)(p * KWW + sl) * HD + q;
            if (p <= t - 2) {
                if (nf == 0) f0 = base;
                else if (nf == 1) f1 = base;
                else if (nf == 2) f2 = base;
                else if (nf == 3) f3 = base;
                nf++;
            } else {   // p == t-1
                if (nn == 0) n0 = base;
                else if (nn == 1) n1 = base;
                else n2 = base;
                nn++;
            }
        }

        // ===== combined poll: h_{t-1} + first FMAX far rows, all in flight =====
        unsigned int hu[8], r0[8], r1[8], r2[8], r3[8];
        if (t > 0 || nf > 0) {
            const unsigned int* hp = hfu + (size_t)(t - 1) * HD + q;
            for (;;) {
                bool ok = true;
                if (t > 0) ok &= ld_row8(hp, hu);
                if (f0)    ok &= ld_row8(f0, r0);
                if (f1)    ok &= ld_row8(f1, r1);
                if (f2)    ok &= ld_row8(f2, r2);
                if (f3)    ok &= ld_row8(f3, r3);
                if (__all(ok)) break;
                __builtin_amdgcn_s_sleep(1);
            }
        }
        float hv[8];
        if (t > 0) {
            #pragma unroll
            for (int i = 0; i < 8; ++i) hv[i] = __builtin_bit_cast(float, hu[i]);
        } else {
            #pragma unroll
            for (int i = 0; i < 8; ++i) hv[i] = 0.f;
        }

        // ===== one merged 6-way GEMV + interleaved wave reduction =====
        float z[6];
        #pragma unroll
        for (int k = 0; k < 6; ++k) z[k] = 0.f;
        #pragma unroll
        for (int i = 0; i < 8; ++i)
            #pragma unroll
            for (int k = 0; k < 6; ++k) z[k] = fmaf(hv[i], wreg[k][i], z[k]);
        #pragma unroll
        for (int m = 1; m < 64; m <<= 1)
            #pragma unroll
            for (int k = 0; k < 6; ++k) z[k] += __shfl_xor(z[k], m, 64);

        // ===== born cells (start t-1): publish ASAP (len-2 consumers poll these) =====
        if (t > 0 && q < KWW) {
            float cv = sigf(wwf + z[3]) * c_prev + sigf(wwi + z[4]) * tanhf(wwg + z[5]);
            stg_a(&c_buf[(size_t)((t - 1) * KWW + q) * HD + ch], cv);
        }

        // ===== merge =====
        float gi = sigf(z[0] + wi0);
        float go = sigf(z[1] + wi1);
        float gg = tanhf(z[2] + wi2);
        float c1;
        if (nv > 0) {
            float wiE = expf(gi);
            float num = wiE * gg, den = wiE;
            auto alpha_acc = [&](const unsigned int ru[8]) {
                float acc = 0.f;
                #pragma unroll
                for (int i = 0; i < 8; ++i)
                    acc = fmaf(__builtin_bit_cast(float, ru[i]), aw[i], acc);
                acc = wave_red(acc);
                float cv_ = 0.f;
                #pragma unroll
                for (int i = 0; i < 8; ++i)
                    if (i == chHi) cv_ = __builtin_bit_cast(float, ru[i]);
                cv_ = __shfl(cv_, chLo);
                float wa = expf(sigf(wi3 + acc));
                num = fmaf(wa, cv_, num);
                den += wa;
            };
            if (f0) alpha_acc(r0);
            if (f1) alpha_acc(r1);
            if (f2) alpha_acc(r2);
            if (f3) alpha_acc(r3);
            // rare overflow: far rows beyond FMAX, polled one at a time
            if (nf > FMAX) {
                int fseen = 0;
                for (int vi = 0; vi < nv; ++vi) {
                    int e = __shfl(mrow, vi);
                    int p = e >> 2, sl = e & 3;
                    if (p > t - 2) continue;
                    fseen++;
                    if (fseen <= FMAX) continue;
                    const unsigned int* base = cbu + (size_t)(p * KWW + sl) * HD + q;
                    unsigned int ru[8];
                    for (;;) {
                        if (__all(ld_row8(base, ru))) break;
                        __builtin_amdgcn_s_sleep(1);
                    }
                    alpha_acc(ru);
                }
            }
            // near rows (len-2 words born this step by all blocks): poll together
            if (nn > 0) {
                unsigned int a0[8], a1[8], a2[8];
                for (;;) {
                    bool ok = true;
                    if (n0) ok &= ld_row8(n0, a0);
                    if (n1) ok &= ld_row8(n1, a1);
                    if (n2) ok &= ld_row8(n2, a2);
                    if (__all(ok)) break;
                    __builtin_amdgcn_s_sleep(1);
                }
                if (n0) alpha_acc(a0);
                if (n1) alpha_acc(a1);
                if (n2) alpha_acc(a2);
            }
            c1 = num / den;
        } else {
            c1 = (1.f - gi) * c_prev + gi * gg;
        }
        float h1 = go * tanhf(c1);
        c_prev = c1;
        if (q == 0) {
            stg_a(&hfull[(size_t)t * HD + ch], h1);
            if (mode) {
                unsigned short* o = (unsigned short*)outp;
                o[(size_t)t * HD + ch] = f2bf(h1);
                o[(size_t)SEQ * HD + (size_t)t * HD + ch] = f2bf(c1);
            } else {
                float* o = (float*)outp;
                o[(size_t)t * HD + ch] = h1;
                o[(size_t)SEQ * HD + (size_t)t * HD + ch] = c1;
            }
        }
        // no barriers, no LDS: the polls ARE the synchronization
    }
}

extern "C" void kernel_launch(void* const* d_in, const int* in_sizes, int n_in,
                              void* d_out, int out_size, void* d_ws, size_t ws_size,
                              hipStream_t stream) {
    const void* x     = d_in[0];
    const void* W_ih  = d_in[1];
    const void* W_hh  = d_in[2];
    const void* bb    = d_in[3];
    const void* aW_ih = d_in[4];
    const void* aW_hh = d_in[5];
    const void* ab    = d_in[6];
    const void* Ww_ih = d_in[7];
    const void* Ww_hh = d_in[8];
    const void* bw    = d_in[9];
    const void* wemb  = d_in[10];
    const int* wids  = (const int*)d_in[11];
    const int* gpos  = (const int*)d_in[12];
    const int* gslot = (const int*)d_in[13];
    const unsigned char* gmask = (const unsigned char*)d_in[14];

    int Km = in_sizes[12] / SEQ;
    if (Km > 32) Km = 32;
    if (ws_size < WS_END) return;

    char* ws = (char*)d_ws;
    int*   flags = (int*)(ws + WS_FLAGS);
    int*   cnt   = (int*)(ws + WS_CNT);
    float* c_buf = (float*)(ws + WS_CBUF);
    float* hfull = (float*)(ws + WS_HFULL);
    int*   mhdr  = (int*)(ws + WS_MHDR);
    int*   mrows = (int*)(ws + WS_MROWS);
    float* WIb   = (float*)(ws + WS_WIB);
    float* AWIb  = (float*)(ws + WS_AWIB);
    float* WWIb  = (float*)(ws + WS_WWIB);
    float* WT    = (float*)(ws + WS_WT);

    hipMemsetAsync(ws, 0, WS_ZEROSZ, stream);                         // flags/cnt
    hipMemsetAsync(ws + WS_CBUF, 0xFF, WS_FFEND - WS_CBUF, stream);   // sentinel buffers
    detect_kernel<<<1, 256, 0, stream>>>((const unsigned int*)W_ih, cnt);
    transpose_cat_kernel<<<dim3(ZT / 32, HD / 32), 256, 0, stream>>>(
        W_hh, Ww_hh, cnt, WT);
    gemm_bias_kernel<false><<<dim3(TH3 / 64, SEQ / 64), 256, 0, stream>>>(
        x, W_ih, bb, nullptr, cnt, WIb, SEQ, TH3, HD);
    gemm_bias_kernel<false><<<dim3(HD / 64, SEQ / 64), 256, 0, stream>>>(
        x, aW_ih, ab, nullptr, cnt, AWIb, SEQ, HD, HD);
    gemm_bias_kernel<true><<<dim3(TH3 / 64, (SEQ * KWW) / 64), 256, 0, stream>>>(
        wemb, Ww_ih, bw, wids, cnt, WWIb, SEQ * KWW, TH3, HD);
    lattice_scan<<<GRID, NT, 0, stream>>>(
        WT, aW_hh, WIb, AWIb, WWIb,
        hfull, c_buf, flags, cnt,
        gpos, gslot, gmask, mhdr, mrows, d_out, Km);
}